// Round 1
// baseline (626.332 us; speedup 1.0000x reference)
//
#include <hip/hip_runtime.h>
#include <hip/hip_cooperative_groups.h>
#include <math.h>

namespace cg = cooperative_groups;

#define MSZ 4096
#define ISZ 2048
#define NSPLIT 64
#define KC (ISZ / NSPLIT)        // 32 rows per split
#define NBLK (3 * 4 * NSPLIT)    // 768 blocks = 3 blocks/CU exactly
#define NTHR 256

typedef float fx4 __attribute__((ext_vector_type(4)));

// ---------------------------------------------------------------------------
// Fused cooperative kernel: phase 1 split-K matvec partials -> grid sync ->
// phase 2 reduce+activations (h_t) -> grid sync -> phase 3 outer product.
// One dispatch instead of three: removes two full kernel-boundary drains
// (end-of-kernel waitcnt + L2 flush + dispatch ramp) which the 436.7us
// baseline (vs ~27us traffic roofline) suggests dominate.
// ---------------------------------------------------------------------------
__global__ void __launch_bounds__(NTHR, 3) k_fused(
    const float* __restrict__ x,
    const float* __restrict__ w_inpgate,
    const float* __restrict__ w_outgate,
    const float* __restrict__ w_inp,
    const float* __restrict__ b_inpgate,
    const float* __restrict__ b_outgate,
    const float* __restrict__ b_inp,
    const float* __restrict__ w_hid_out,
    float* __restrict__ z_part,
    float* __restrict__ h_t,
    fx4* __restrict__ out4)
{
    const int b = blockIdx.x;
    const int t = threadIdx.x;

    // ---- Phase 1: split-K partial matvec for the 3 live gates --------------
    {
        const int gate    = b / (4 * NSPLIT);
        const int rem     = b % (4 * NSPLIT);
        const int coltile = rem / NSPLIT;
        const int split   = rem % NSPLIT;

        const float* W = (gate == 0) ? w_inpgate : (gate == 1) ? w_outgate : w_inp;
        const fx4* W4 = (const fx4*)W;

        const int c4 = coltile * 256 + t;   // float4 column index, 0..1023
        const int k0 = split * KC;

        fx4 acc = {0.f, 0.f, 0.f, 0.f};
        #pragma unroll 8
        for (int ii = 0; ii < KC; ++ii) {
            const float xi = x[k0 + ii];                       // wave-uniform s_load
            // Weights are streamed exactly once: nontemporal keeps L2 for z_part.
            const fx4 w = __builtin_nontemporal_load(
                &W4[(size_t)(k0 + ii) * (MSZ / 4) + c4]);
            acc += xi * w;
        }
        ((fx4*)z_part)[((size_t)split * 3 + gate) * (MSZ / 4) + c4] = acc;
    }

    cg::this_grid().sync();

    // ---- Phase 2: reduce partials + bias + LSTM activations ----------------
    // h_t[j] = sigmoid(z_o) * tanh( sigmoid(z_i) * tanh(z_c) )   (c0 == 0)
    if (b < MSZ / NTHR) {                     // first 16 blocks
        const int j = b * NTHR + t;           // 0..4095
        float zi = b_inpgate[j];
        float zo = b_outgate[j];
        float zc = b_inp[j];
        #pragma unroll 8
        for (int s = 0; s < NSPLIT; ++s) {
            const float* zp = z_part + (size_t)s * 3 * MSZ;
            zi += zp[0 * MSZ + j];
            zo += zp[1 * MSZ + j];
            zc += zp[2 * MSZ + j];
        }
        const float ig  = 1.f / (1.f + __expf(-zi));
        const float og  = 1.f / (1.f + __expf(-zo));
        const float ct  = tanhf(zc);
        const float c_t = ig * ct;            // forget_gate * c0 == 0
        h_t[j] = og * tanhf(c_t);
    }

    cg::this_grid().sync();

    // ---- Phase 3: outer product out[i][j] = w_hid_out[i] * h_t[j] ----------
    // 4M float4 nontemporal stores, grid-strided over all 768 blocks.
    {
        const fx4* h4 = (const fx4*)h_t;
        const int total4 = MSZ * (MSZ / 4);   // 4,194,304
        for (int i = b * NTHR + t; i < total4; i += NBLK * NTHR) {
            const int row = i >> 10;          // / (4096/4)
            const float w = w_hid_out[row];   // wave-uniform, L1-hit
            const fx4 o = w * h4[i & 1023];   // h_t: 16 KiB, L1/L2-resident
            __builtin_nontemporal_store(o, &out4[i]);
        }
    }
}

// ---------------------------------------------------------------------------
// Fallback path: the previously harness-verified 3-kernel pipeline, used only
// if the cooperative launch is rejected (keeps the round from being lost).
// ---------------------------------------------------------------------------
__global__ void k_matvec(const float* __restrict__ x,
                         const float* __restrict__ w_inpgate,
                         const float* __restrict__ w_outgate,
                         const float* __restrict__ w_inp,
                         float* __restrict__ z_part)
{
    const int b = blockIdx.x;
    const int gate = b / (4 * NSPLIT);
    const int rem = b % (4 * NSPLIT);
    const int coltile = rem / NSPLIT;
    const int split = rem % NSPLIT;

    const float* W = (gate == 0) ? w_inpgate : (gate == 1) ? w_outgate : w_inp;
    const fx4* W4 = (const fx4*)W;

    const int c4 = coltile * 256 + threadIdx.x;
    const int k0 = split * KC;

    fx4 acc = {0.f, 0.f, 0.f, 0.f};
    #pragma unroll 8
    for (int ii = 0; ii < KC; ++ii) {
        const float xi = x[k0 + ii];
        const fx4 w = W4[(size_t)(k0 + ii) * (MSZ / 4) + c4];
        acc += xi * w;
    }
    fx4* zp4 = (fx4*)z_part;
    zp4[((size_t)split * 3 + gate) * (MSZ / 4) + c4] = acc;
}

__global__ void k_act(const float* __restrict__ z_part,
                      const float* __restrict__ b_inpgate,
                      const float* __restrict__ b_outgate,
                      const float* __restrict__ b_inp,
                      float* __restrict__ h_t)
{
    const int j = blockIdx.x * 256 + threadIdx.x;
    float zi = b_inpgate[j];
    float zo = b_outgate[j];
    float zc = b_inp[j];
    #pragma unroll 8
    for (int s = 0; s < NSPLIT; ++s) {
        const float* zp = z_part + (size_t)s * 3 * MSZ;
        zi += zp[0 * MSZ + j];
        zo += zp[1 * MSZ + j];
        zc += zp[2 * MSZ + j];
    }
    const float ig = 1.f / (1.f + __expf(-zi));
    const float og = 1.f / (1.f + __expf(-zo));
    const float ct = tanhf(zc);
    const float c_t = ig * ct;
    h_t[j] = og * tanhf(c_t);
}

__global__ void k_outer(const float* __restrict__ w_hid_out,
                        const float* __restrict__ h_t,
                        fx4* __restrict__ out4)
{
    const int tid = blockIdx.x * 256 + threadIdx.x;
    const int row = tid >> 10;
    const int j4 = tid & 1023;
    const float w = w_hid_out[row];
    const fx4 h = ((const fx4*)h_t)[j4];
    const fx4 o = w * h;
    __builtin_nontemporal_store(o, &out4[tid]);
}

extern "C" void kernel_launch(void* const* d_in, const int* in_sizes, int n_in,
                              void* d_out, int out_size, void* d_ws, size_t ws_size,
                              hipStream_t stream) {
    const float* x          = (const float*)d_in[0];
    // h0 = d_in[1], c0 = d_in[2]: zeros, unused (is_reset==1)
    const float* w_inpgate  = (const float*)d_in[3];
    const float* w_inp      = (const float*)d_in[6];
    const float* w_outgate  = (const float*)d_in[11];
    const float* w_hid_out  = (const float*)d_in[14];
    const float* b_inpgate  = (const float*)d_in[15];
    const float* b_inp      = (const float*)d_in[16];
    const float* b_outgate  = (const float*)d_in[18];

    float* z_part = (float*)d_ws;                       // 64 * 3 * 4096 floats = 3 MiB
    float* h_t    = z_part + (size_t)NSPLIT * 3 * MSZ;  // 4096 floats
    fx4*   out4   = (fx4*)d_out;

    void* args[] = {
        (void*)&x,
        (void*)&w_inpgate, (void*)&w_outgate, (void*)&w_inp,
        (void*)&b_inpgate, (void*)&b_outgate, (void*)&b_inp,
        (void*)&w_hid_out,
        (void*)&z_part, (void*)&h_t, (void*)&out4
    };

    hipError_t err = hipLaunchCooperativeKernel(
        (void*)k_fused, dim3(NBLK), dim3(NTHR), args, 0, stream);

    if (err != hipSuccess) {
        // Fallback: previously-verified 3-kernel pipeline.
        k_matvec<<<3 * 4 * NSPLIT, 256, 0, stream>>>(x, w_inpgate, w_outgate, w_inp, z_part);
        k_act<<<MSZ / 256, 256, 0, stream>>>(z_part, b_inpgate, b_outgate, b_inp, h_t);
        k_outer<<<(MSZ * (MSZ / 4)) / 256, 256, 0, stream>>>(w_hid_out, h_t, out4);
    }
}

// Round 3
// 440.629 us; speedup vs baseline: 1.4215x; 1.4215x over previous
//
#include <hip/hip_runtime.h>
#include <math.h>

#define MSZ 4096
#define ISZ 2048
#define NSPLIT 64
#define KC (ISZ / NSPLIT)   // 32 rows per split

typedef float fx4 __attribute__((ext_vector_type(4)));

// ---------------------------------------------------------------------------
// Kernel A: split-K partial matvec for the 3 live gates (inpgate, outgate, inp)
// grid = 3 gates x 4 coltiles x NSPLIT splits = 768 blocks = 3 blocks/CU.
// Changes vs baseline:
//  - plain loads (no nontemporal): 96 MB of weights fit in the 256 MB L3, so
//    steady-state bench iterations should serve from Infinity Cache.
//  - x slice hoisted into registers before the hot loop (no lgkm waits inside).
//  - full unroll with TWO independent accumulator chains so the compiler can
//    keep ~16+ weight loads in flight instead of draining every 8.
// ---------------------------------------------------------------------------
__global__ __launch_bounds__(256, 3) void k_matvec(
    const float* __restrict__ x,
    const float* __restrict__ w_inpgate,
    const float* __restrict__ w_outgate,
    const float* __restrict__ w_inp,
    float* __restrict__ z_part)
{
    const int b       = blockIdx.x;
    const int gate    = b / (4 * NSPLIT);
    const int rem     = b % (4 * NSPLIT);
    const int coltile = rem / NSPLIT;
    const int split   = rem % NSPLIT;

    const float* W = (gate == 0) ? w_inpgate : (gate == 1) ? w_outgate : w_inp;
    const fx4* W4  = (const fx4*)W + (size_t)split * KC * (MSZ / 4);

    const int c4 = coltile * 256 + threadIdx.x;   // float4 column index, 0..1023

    // Hoist the 32 x-values for this split (wave-uniform -> scalar regs).
    float xr[KC];
    #pragma unroll
    for (int i = 0; i < KC; ++i) xr[i] = x[split * KC + i];

    fx4 acc0 = {0.f, 0.f, 0.f, 0.f};
    fx4 acc1 = {0.f, 0.f, 0.f, 0.f};
    #pragma unroll
    for (int ii = 0; ii < KC; ii += 2) {
        acc0 += xr[ii]     * W4[(size_t)(ii)     * (MSZ / 4) + c4];
        acc1 += xr[ii + 1] * W4[(size_t)(ii + 1) * (MSZ / 4) + c4];
    }
    ((fx4*)z_part)[((size_t)split * 3 + gate) * (MSZ / 4) + c4] = acc0 + acc1;
}

// ---------------------------------------------------------------------------
// Kernel B: reduce NSPLIT partials per (gate, col), add bias, LSTM activations.
// h_t[j] = sigmoid(z_o) * tanh( sigmoid(z_i) * tanh(z_c) )   (c0 == 0)
// 3 MB of partials, L2/L3-resident. Two-way split of the split-loop for MLP.
// ---------------------------------------------------------------------------
__global__ __launch_bounds__(256) void k_act(
    const float* __restrict__ z_part,
    const float* __restrict__ b_inpgate,
    const float* __restrict__ b_outgate,
    const float* __restrict__ b_inp,
    float* __restrict__ h_t)
{
    const int j = blockIdx.x * 256 + threadIdx.x;  // 0..4095
    float zi0 = b_inpgate[j], zi1 = 0.f;
    float zo0 = b_outgate[j], zo1 = 0.f;
    float zc0 = b_inp[j],     zc1 = 0.f;
    #pragma unroll 8
    for (int s = 0; s < NSPLIT; s += 2) {
        const float* zp0 = z_part + (size_t)(s)     * 3 * MSZ;
        const float* zp1 = z_part + (size_t)(s + 1) * 3 * MSZ;
        zi0 += zp0[0 * MSZ + j];  zi1 += zp1[0 * MSZ + j];
        zo0 += zp0[1 * MSZ + j];  zo1 += zp1[1 * MSZ + j];
        zc0 += zp0[2 * MSZ + j];  zc1 += zp1[2 * MSZ + j];
    }
    const float zi = zi0 + zi1, zo = zo0 + zo1, zc = zc0 + zc1;
    const float ig  = 1.f / (1.f + __expf(-zi));
    const float og  = 1.f / (1.f + __expf(-zo));
    const float ct  = tanhf(zc);
    const float c_t = ig * ct;            // forget_gate * c0 == 0
    h_t[j] = og * tanhf(c_t);
}

// ---------------------------------------------------------------------------
// Kernel C: outer product out[i][j] = w_hid_out[i] * h_t[j]  (4096x4096 fp32).
// Grid-stride with 2048 blocks (dispatch-rate friendly), one nontemporal
// float4 store per iteration; h_t (16 KB) is L1/L2-resident, w_hid_out row
// value is wave-uniform. Pure write stream: 64 MiB, kept out of L3 via nt
// so the weights stay Infinity-Cache-resident for the next iteration.
// ---------------------------------------------------------------------------
#define CBLK 2048
__global__ __launch_bounds__(256) void k_outer(
    const float* __restrict__ w_hid_out,
    const float* __restrict__ h_t,
    fx4* __restrict__ out4)
{
    const fx4* h4 = (const fx4*)h_t;
    int i = blockIdx.x * 256 + threadIdx.x;
    #pragma unroll
    for (int it = 0; it < (MSZ * (MSZ / 4)) / (CBLK * 256); ++it, i += CBLK * 256) {
        const int row = i >> 10;            // / (4096/4)
        const float w = w_hid_out[row];
        const fx4 o = w * h4[i & 1023];
        __builtin_nontemporal_store(o, &out4[i]);
    }
}

extern "C" void kernel_launch(void* const* d_in, const int* in_sizes, int n_in,
                              void* d_out, int out_size, void* d_ws, size_t ws_size,
                              hipStream_t stream) {
    const float* x          = (const float*)d_in[0];
    // h0 = d_in[1], c0 = d_in[2]: zeros, unused (is_reset==1)
    const float* w_inpgate  = (const float*)d_in[3];
    const float* w_inp      = (const float*)d_in[6];
    const float* w_outgate  = (const float*)d_in[11];
    const float* w_hid_out  = (const float*)d_in[14];
    const float* b_inpgate  = (const float*)d_in[15];
    const float* b_inp      = (const float*)d_in[16];
    const float* b_outgate  = (const float*)d_in[18];

    float* z_part = (float*)d_ws;                       // 64 * 3 * 4096 floats = 3 MiB
    float* h_t    = z_part + (size_t)NSPLIT * 3 * MSZ;  // 4096 floats

    k_matvec<<<3 * 4 * NSPLIT, 256, 0, stream>>>(x, w_inpgate, w_outgate, w_inp, z_part);
    k_act<<<MSZ / 256, 256, 0, stream>>>(z_part, b_inpgate, b_outgate, b_inp, h_t);
    k_outer<<<CBLK, 256, 0, stream>>>(w_hid_out, h_t, (fx4*)d_out);
}